// Round 6
// baseline (1360.298 us; speedup 1.0000x reference)
//
#include <hip/hip_runtime.h>
#include <hip/hip_bf16.h>

typedef __hip_bfloat16  bf16;
typedef __hip_bfloat162 bf162;

// Problem constants (fixed by reference)
constexpr int Dm  = 1024;    // d_model
constexpr int NH  = 16;      // heads
constexpr int HD  = 64;      // head dim
constexpr int SQ  = 2048;    // seq len
constexpr int BB  = 2;       // batch
constexpr int MM  = BB * SQ; // 4096 rows

__device__ __forceinline__ float ldf(const float* p, size_t i) { return p[i]; }
__device__ __forceinline__ float ldf(const bf16*  p, size_t i) { return __bfloat162float(p[i]); }
__device__ __forceinline__ void storeval(float* p, float v) { *p = v; }
__device__ __forceinline__ void storeval(bf16*  p, float v) { *p = __float2bfloat16(v); }

// ---------------------------------------------------------------------------
// C = A @ W^T + bias. A:[M,K] (fp32 or bf16), W:[N,K] fp32 (torch Linear).
// HEAD_SPLIT: write C as [B,H,S,HD]; else [M,N]. fp32 accumulate.
// 128x128 tile, BK=16, 256 threads, 8x8/thread, LDS pad 17 (conflict-free).
// ---------------------------------------------------------------------------
template<bool HEAD_SPLIT, typename TA, typename OutT>
__global__ __launch_bounds__(256) void gemm_bias(const TA* __restrict__ A,
                                                 const float* __restrict__ W,
                                                 const float* __restrict__ bias,
                                                 OutT* __restrict__ C,
                                                 int K, int N)
{
    __shared__ float As[128][17];
    __shared__ float Ws[128][17];
    const int t  = threadIdx.x;
    const int tx = t & 15;
    const int ty = t >> 4;
    const int n0 = blockIdx.x * 128;
    const int m0 = blockIdx.y * 128;

    float acc[8][8] = {};
    const int lc = t & 15;   // k col 0..15
    const int lr = t >> 4;   // base row 0..15

    for (int k0 = 0; k0 < K; k0 += 16) {
#pragma unroll
        for (int i = 0; i < 8; ++i) {
            As[lr + 16*i][lc] = ldf(A, (size_t)(m0 + lr + 16*i) * K + k0 + lc);
            Ws[lr + 16*i][lc] = W[(size_t)(n0 + lr + 16*i) * K + k0 + lc];
        }
        __syncthreads();
#pragma unroll
        for (int kk = 0; kk < 16; ++kk) {
            float a[8], w[8];
#pragma unroll
            for (int i = 0; i < 8; ++i) a[i] = As[ty + 16*i][kk];
#pragma unroll
            for (int j = 0; j < 8; ++j) w[j] = Ws[tx + 16*j][kk];
#pragma unroll
            for (int i = 0; i < 8; ++i)
#pragma unroll
                for (int j = 0; j < 8; ++j)
                    acc[i][j] += a[i] * w[j];
        }
        __syncthreads();
    }

#pragma unroll
    for (int i = 0; i < 8; ++i) {
        const int m = m0 + ty + 16*i;
#pragma unroll
        for (int j = 0; j < 8; ++j) {
            const int n = n0 + tx + 16*j;
            float v = acc[i][j] + bias[n];
            size_t idx;
            if (HEAD_SPLIT) {
                const int b  = m >> 11;   // m / 2048 (S fixed)
                const int s  = m & 2047;
                const int h  = n >> 6;    // n / 64
                const int hd = n & 63;
                idx = ((size_t)((b * NH + h) * SQ + s) << 6) | (size_t)hd;
            } else {
                idx = (size_t)m * N + n;
            }
            storeval(&C[idx], v);
        }
    }
}

// ---------------------------------------------------------------------------
// Evidential attention. One block = one (b,h) head x 64-query tile.
// evidence = exp(score/8)*scale + (1+bias); denom = row sum; attn = E@V/denom.
// Q/K/V are bf16 scratch we wrote ourselves; esc/ebi fp32 inputs.
// Writes attn (bf16, ws) + denoms (fp32, ws). Never touches d_out.
// ---------------------------------------------------------------------------
__global__ __launch_bounds__(256) void attention(const bf16* __restrict__ Qg,
                                                 const bf16* __restrict__ Kg,
                                                 const bf16* __restrict__ Vg,
                                                 const float* __restrict__ esc,
                                                 const float* __restrict__ ebi,
                                                 bf16* __restrict__ attn,
                                                 float* __restrict__ denoms)
{
    __shared__ float Qs[64][65];
    __shared__ float Ks[64][65];
    __shared__ float Vs[64][65];
    __shared__ float Es[64][65];
    __shared__ float red[64][17];
    __shared__ float dinv[64];

    const int t  = threadIdx.x;
    const int tx = t & 15;
    const int ty = t >> 4;
    const int qt = blockIdx.x & 31;   // S/64 = 32 query tiles
    const int bh = blockIdx.x >> 5;   // b*NH + h, 0..31
    const int q0 = qt * 64;

    const float scale = esc[0];
    const float bias1 = 1.0f + ebi[0];
    const size_t headBase = (size_t)bh * SQ * HD;

    // Load 64x64 Q tile (64 bf16/row = 32 bf162/row).
    {
        const bf162* src = (const bf162*)(Qg + headBase + (size_t)q0 * HD);
#pragma unroll
        for (int i = 0; i < 8; ++i) {
            int idx = t + 256 * i;
            int r = idx >> 5;
            int c = idx & 31;
            bf162 v = src[r * 32 + c];
            Qs[r][2*c]   = __low2float(v);
            Qs[r][2*c+1] = __high2float(v);
        }
    }

    float acc[4][4] = {};
    float drow[4] = {};

    for (int kt = 0; kt < SQ / 64; ++kt) {
        __syncthreads();   // prior iter's readers done (and Qs visible, 1st iter)
        const bf162* ksrc = (const bf162*)(Kg + headBase + (size_t)kt * 64 * HD);
        const bf162* vsrc = (const bf162*)(Vg + headBase + (size_t)kt * 64 * HD);
#pragma unroll
        for (int i = 0; i < 8; ++i) {
            int idx = t + 256 * i;
            int r = idx >> 5;
            int c = idx & 31;
            bf162 kv = ksrc[r * 32 + c];
            Ks[r][2*c]   = __low2float(kv);
            Ks[r][2*c+1] = __high2float(kv);
            bf162 vv = vsrc[r * 32 + c];
            Vs[r][2*c]   = __low2float(vv);
            Vs[r][2*c+1] = __high2float(vv);
        }
        __syncthreads();

        // scores -> evidence for this thread's 4x4 cells
        {
            float s_[4][4] = {};
#pragma unroll 8
            for (int d = 0; d < 64; ++d) {
                float a[4], b[4];
#pragma unroll
                for (int i = 0; i < 4; ++i) a[i] = Qs[ty + 16*i][d];
#pragma unroll
                for (int j = 0; j < 4; ++j) b[j] = Ks[tx + 16*j][d];
#pragma unroll
                for (int i = 0; i < 4; ++i)
#pragma unroll
                    for (int j = 0; j < 4; ++j)
                        s_[i][j] += a[i] * b[j];
            }
#pragma unroll
            for (int i = 0; i < 4; ++i)
#pragma unroll
                for (int j = 0; j < 4; ++j) {
                    float ev = expf(s_[i][j] * 0.125f) * scale + bias1;
                    Es[ty + 16*i][tx + 16*j] = ev;
                    drow[i] += ev;
                }
        }
        __syncthreads();   // Es fully written before cross-thread reads

        // acc += Es @ Vs
#pragma unroll 8
        for (int kk = 0; kk < 64; ++kk) {
            float ee[4], vv[4];
#pragma unroll
            for (int i = 0; i < 4; ++i) ee[i] = Es[ty + 16*i][kk];
#pragma unroll
            for (int j = 0; j < 4; ++j) vv[j] = Vs[kk][tx + 16*j];
#pragma unroll
            for (int i = 0; i < 4; ++i)
#pragma unroll
                for (int j = 0; j < 4; ++j)
                    acc[i][j] += ee[i] * vv[j];
        }
    }

    // denom: reduce 16 tx partials per query row
    __syncthreads();
#pragma unroll
    for (int i = 0; i < 4; ++i)
        red[ty + 16*i][tx] = drow[i];
    __syncthreads();
    if (t < 64) {
        float d = 0.f;
#pragma unroll
        for (int x = 0; x < 16; ++x) d += red[t][x];
        denoms[(size_t)bh * SQ + q0 + t] = d;
        dinv[t] = 1.0f / d;
    }
    __syncthreads();

    const int b = bh >> 4;
    const int h = bh & 15;
#pragma unroll
    for (int i = 0; i < 4; ++i) {
        const int q = ty + 16*i;
        const float di = dinv[q];
        bf16* dst = attn + ((size_t)(b * SQ + q0 + q)) * Dm + h * HD;
#pragma unroll
        for (int j = 0; j < 4; ++j)
            dst[tx + 16*j] = __float2bfloat16(acc[i][j] * di);
    }
}

// uncertainty = S / denom  (fp32, output 1 region of d_out)
__global__ void write_unc(const float* __restrict__ denoms, float* __restrict__ unc)
{
    const int g = blockIdx.x * 256 + threadIdx.x;   // 0..65535
    unc[g] = (float)SQ / denoms[g];
}

extern "C" void kernel_launch(void* const* d_in, const int* in_sizes, int n_in,
                              void* d_out, int out_size, void* d_ws, size_t ws_size,
                              hipStream_t stream)
{
    const float* x   = (const float*)d_in[0];
    const float* qw  = (const float*)d_in[1];
    const float* qb  = (const float*)d_in[2];
    const float* kw  = (const float*)d_in[3];
    const float* kb  = (const float*)d_in[4];
    const float* vw  = (const float*)d_in[5];
    const float* vb  = (const float*)d_in[6];
    const float* ow  = (const float*)d_in[7];
    const float* ob  = (const float*)d_in[8];
    const float* esc = (const float*)d_in[9];
    const float* ebi = (const float*)d_in[10];

    float* out = (float*)d_out;                       // output 0: [B,S,D] fp32
    float* unc = out + (size_t)BB * SQ * Dm;          // output 1: [B,H,S] fp32

    // ws: [denoms fp32 256KB @0 | Qb @512KB | Kb | Vb | Ab] (bf16, 8MB each)
    float* denoms = (float*)d_ws;
    bf16*  Qb = (bf16*)((char*)d_ws + (512 << 10));
    bf16*  Kb = Qb + (size_t)BB * SQ * Dm;
    bf16*  Vb = Kb + (size_t)BB * SQ * Dm;
    bf16*  Ab = Vb + (size_t)BB * SQ * Dm;

    dim3 blkG(256);
    dim3 grdG(Dm / 128, MM / 128);   // (8, 32)

    gemm_bias<true,  float, bf16><<<grdG, blkG, 0, stream>>>(x, qw, qb, Qb, Dm, Dm);
    gemm_bias<true,  float, bf16><<<grdG, blkG, 0, stream>>>(x, kw, kb, Kb, Dm, Dm);
    gemm_bias<true,  float, bf16><<<grdG, blkG, 0, stream>>>(x, vw, vb, Vb, Dm, Dm);

    attention<<<dim3(BB * NH * (SQ / 64)), blkG, 0, stream>>>(Qb, Kb, Vb, esc, ebi,
                                                              Ab, denoms);

    write_unc<<<dim3(BB * NH * SQ / 256), blkG, 0, stream>>>(denoms, unc);

    gemm_bias<false, bf16, float><<<grdG, blkG, 0, stream>>>(Ab, ow, ob, out, Dm, Dm);
}

// Round 7
// 303.476 us; speedup vs baseline: 4.4824x; 4.4824x over previous
//
#include <hip/hip_runtime.h>

typedef __attribute__((ext_vector_type(8))) short bf16x8;  // 8 bf16 = 4 VGPRs (MFMA A/B frag)
typedef __attribute__((ext_vector_type(4))) float f32x4;   // MFMA C/D frag

constexpr int Dm  = 1024;    // d_model
constexpr int NH  = 16;      // heads
constexpr int HD  = 64;      // head dim
constexpr int SQ  = 2048;    // seq len
constexpr int BB  = 2;       // batch
constexpr int MM  = BB * SQ; // 4096 rows

// fp32 -> bf16 bits, round-to-nearest-even (values finite; no NaN path needed)
__device__ __forceinline__ unsigned short f2bf(float f) {
    unsigned int u = __float_as_uint(f);
    u += 0x7FFFu + ((u >> 16) & 1u);
    return (unsigned short)(u >> 16);
}

// ---------------------------------------------------------------------------
// cast fp32 -> bf16 bits, 4 elems/thread
// ---------------------------------------------------------------------------
__global__ void cast_bf16(const float4* __restrict__ in, uint2* __restrict__ out, int n4)
{
    int i = blockIdx.x * 256 + threadIdx.x;
    if (i < n4) {
        float4 v = in[i];
        uint2 o;
        o.x = (unsigned)f2bf(v.x) | ((unsigned)f2bf(v.y) << 16);
        o.y = (unsigned)f2bf(v.z) | ((unsigned)f2bf(v.w) << 16);
        out[i] = o;
    }
}

// ---------------------------------------------------------------------------
// MFMA GEMM: C = A(bf16)[M=4096,K=1024] @ W(fp32,[N,K])^T + bias.
// Block: 64(m) x 128(n) tile, BK=32, 256 thr = 4 waves (2x2, wave tile 32x64).
// W is converted fp32->bf16 while staging to LDS.
// MODE 0: head-split ushort [B,H,S,HD] (Q,K)
// MODE 1: transposed head-split ushort [B,H,HD,S] (V^T, for attention B-operand)
// MODE 2: fp32 row-major [M,N] (final out)
// LDS row stride 56 ushort = 112 B (16B-aligned, 2-way banks only).
// ---------------------------------------------------------------------------
template<int MODE>
__global__ __launch_bounds__(256) void gemm_mfma(const unsigned short* __restrict__ A,
                                                 const float* __restrict__ W,
                                                 const float* __restrict__ bias,
                                                 void* __restrict__ Cv)
{
    __shared__ unsigned short As[64 * 56];
    __shared__ unsigned short Ws[128 * 56];
    const int t    = threadIdx.x;
    const int lane = t & 63, w = t >> 6;
    const int lm   = lane & 15, quad = lane >> 4;
    const int wm   = w & 1,  wn = w >> 1;
    const int n0   = blockIdx.x * 128, m0 = blockIdx.y * 64;

    const f32x4 fz = {0.f, 0.f, 0.f, 0.f};
    f32x4 acc[2][4];
#pragma unroll
    for (int mi = 0; mi < 2; ++mi)
#pragma unroll
        for (int ni = 0; ni < 4; ++ni) acc[mi][ni] = fz;

    float bsv[4];
#pragma unroll
    for (int ni = 0; ni < 4; ++ni) bsv[ni] = bias[n0 + wn * 64 + ni * 16 + lm];

    for (int k0 = 0; k0 < 1024; k0 += 32) {
        __syncthreads();   // prev iteration's LDS readers done
        {
            // A: 64 rows x 32 k = 2048 bf16; 1 x uint4 (8 bf16) per thread
            int ar = t >> 2, ac8 = t & 3;
            *(uint4*)&As[ar * 56 + ac8 * 8] =
                *(const uint4*)(A + (size_t)(m0 + ar) * 1024 + k0 + ac8 * 8);
            // W: 128 rows x 32 k fp32; 4 x float4 per thread, convert to bf16
#pragma unroll
            for (int i = 0; i < 4; ++i) {
                int seg = t + 256 * i;
                int r = seg >> 3, c4 = seg & 7;
                float4 v = *(const float4*)(W + (size_t)(n0 + r) * 1024 + k0 + c4 * 4);
                uint2 o;
                o.x = (unsigned)f2bf(v.x) | ((unsigned)f2bf(v.y) << 16);
                o.y = (unsigned)f2bf(v.z) | ((unsigned)f2bf(v.w) << 16);
                *(uint2*)&Ws[r * 56 + c4 * 4] = o;
            }
        }
        __syncthreads();

        bf16x8 af[2], bfr[4];
#pragma unroll
        for (int mi = 0; mi < 2; ++mi)
            af[mi] = *(const bf16x8*)&As[(wm * 32 + mi * 16 + lm) * 56 + quad * 8];
#pragma unroll
        for (int ni = 0; ni < 4; ++ni)
            bfr[ni] = *(const bf16x8*)&Ws[(wn * 64 + ni * 16 + lm) * 56 + quad * 8];
#pragma unroll
        for (int mi = 0; mi < 2; ++mi)
#pragma unroll
            for (int ni = 0; ni < 4; ++ni)
                acc[mi][ni] = __builtin_amdgcn_mfma_f32_16x16x32_bf16(
                                  af[mi], bfr[ni], acc[mi][ni], 0, 0, 0);
    }

    // Epilogue. C/D layout: col = lane&15, row = quad*4 + reg  [verified m89/m91]
#pragma unroll
    for (int mi = 0; mi < 2; ++mi)
#pragma unroll
        for (int ni = 0; ni < 4; ++ni)
#pragma unroll
            for (int r = 0; r < 4; ++r) {
                const int m = m0 + wm * 32 + mi * 16 + quad * 4 + r;
                const int n = n0 + wn * 64 + ni * 16 + lm;
                const float v = acc[mi][ni][r] + bsv[ni];
                if (MODE == 2) {
                    ((float*)Cv)[(size_t)m * 1024 + n] = v;
                } else {
                    const int b = m >> 11, s = m & 2047, h = n >> 6, hd = n & 63;
                    const size_t idx = (MODE == 0)
                        ? ((size_t)((b * NH + h) * SQ + s) * 64 + hd)
                        : ((size_t)((b * NH + h) * 64 + hd) * SQ + s);
                    ((unsigned short*)Cv)[idx] = f2bf(v);
                }
            }
}

// ---------------------------------------------------------------------------
// MFMA evidential attention. Block = (b,h) x 64-query tile; 4 waves, each a
// 16q strip. Per kt (64 keys): S=Q·K^T (MFMA) -> evidence=exp(s/8)*scale+1+bias
// -> E (bf16, wave-private LDS strip) -> acc += E·V (MFMA, V staged transposed).
// denom per q-row reduced via LDS; writes Ab (bf16 [B,S,D]) + denoms (fp32 ws).
// LDS stride 72 ushort = 144 B: 16B-aligned, 2-way banks (free).
// ---------------------------------------------------------------------------
__global__ __launch_bounds__(256) void attn_mfma(const unsigned short* __restrict__ Qg,
                                                 const unsigned short* __restrict__ Kg,
                                                 const unsigned short* __restrict__ Vtg,
                                                 const float* __restrict__ esc,
                                                 const float* __restrict__ ebi,
                                                 unsigned short* __restrict__ Ab,
                                                 float* __restrict__ denoms)
{
    __shared__ unsigned short Qs[64 * 72];
    __shared__ unsigned short Ks[64 * 72];
    __shared__ unsigned short Vts[64 * 72];      // [d][k_seq]
    __shared__ unsigned short Es[4][16 * 72];    // wave-private E strips [q][k_seq]
    __shared__ float dred[64][17];
    __shared__ float dinv[64];

    const int t    = threadIdx.x;
    const int lane = t & 63, w = t >> 6;
    const int lm   = lane & 15, quad = lane >> 4;
    const int qt   = blockIdx.x & 31;    // 32 query tiles
    const int bh   = blockIdx.x >> 5;    // b*NH + h
    const int q0   = qt * 64;

    const float scale = esc[0];
    const float bias1 = 1.0f + ebi[0];

    // stage Q tile (rows=q, cols=d) once
    {
        const unsigned short* g = Qg + (size_t)(bh * SQ + q0) * 64;
#pragma unroll
        for (int i = 0; i < 2; ++i) {
            int seg = t + 256 * i, r = seg >> 3, c8 = seg & 7;
            *(uint4*)&Qs[r * 72 + c8 * 8] = *(const uint4*)(g + r * 64 + c8 * 8);
        }
    }

    const f32x4 fz = {0.f, 0.f, 0.f, 0.f};
    f32x4 acc[4];
#pragma unroll
    for (int ni = 0; ni < 4; ++ni) acc[ni] = fz;
    float drow[4] = {0.f, 0.f, 0.f, 0.f};

    for (int kt = 0; kt < 32; ++kt) {
        __syncthreads();   // prev iter's Ks/Vts readers done (Qs visible 1st iter)
        {
            const unsigned short* kg = Kg  + (size_t)(bh * SQ + kt * 64) * 64;
            const unsigned short* vg = Vtg + (size_t)bh * 64 * SQ + kt * 64;
#pragma unroll
            for (int i = 0; i < 2; ++i) {
                int seg = t + 256 * i, r = seg >> 3, c8 = seg & 7;
                *(uint4*)&Ks[r * 72 + c8 * 8]  = *(const uint4*)(kg + r * 64 + c8 * 8);
                *(uint4*)&Vts[r * 72 + c8 * 8] = *(const uint4*)(vg + (size_t)r * SQ + c8 * 8);
            }
        }
        __syncthreads();

        // S = Q K^T : A-frag = Q rows (strip-local), B-frag = K rows
        bf16x8 qa[2];
#pragma unroll
        for (int kc = 0; kc < 2; ++kc)
            qa[kc] = *(const bf16x8*)&Qs[(w * 16 + lm) * 72 + kc * 32 + quad * 8];
#pragma unroll
        for (int ni = 0; ni < 4; ++ni) {
            f32x4 s = fz;
#pragma unroll
            for (int kc = 0; kc < 2; ++kc) {
                bf16x8 kb = *(const bf16x8*)&Ks[(ni * 16 + lm) * 72 + kc * 32 + quad * 8];
                s = __builtin_amdgcn_mfma_f32_16x16x32_bf16(qa[kc], kb, s, 0, 0, 0);
            }
#pragma unroll
            for (int r = 0; r < 4; ++r) {
                float ev = __expf(s[r] * 0.125f) * scale + bias1;
                drow[r] += ev;                                   // partial (this lane's col)
                Es[w][(quad * 4 + r) * 72 + ni * 16 + lm] = f2bf(ev);
            }
        }
        __syncthreads();   // Es cross-lane visibility (cheap; also orders LDS)

        // acc += E V  : A-frag = E strip rows, B-frag = Vt rows (=d), k=k_seq
        bf16x8 ea[2];
#pragma unroll
        for (int kc = 0; kc < 2; ++kc)
            ea[kc] = *(const bf16x8*)&Es[w][lm * 72 + kc * 32 + quad * 8];
#pragma unroll
        for (int ni = 0; ni < 4; ++ni)
#pragma unroll
            for (int kc = 0; kc < 2; ++kc) {
                bf16x8 vb = *(const bf16x8*)&Vts[(ni * 16 + lm) * 72 + kc * 32 + quad * 8];
                acc[ni] = __builtin_amdgcn_mfma_f32_16x16x32_bf16(ea[kc], vb, acc[ni], 0, 0, 0);
            }
    }

    // denom: each lane's drow[r] is the partial sum over its col; reduce 16 cols
    __syncthreads();
#pragma unroll
    for (int r = 0; r < 4; ++r)
        dred[w * 16 + quad * 4 + r][lm] = drow[r];
    __syncthreads();
    if (t < 64) {
        float d = 0.f;
#pragma unroll
        for (int c = 0; c < 16; ++c) d += dred[t][c];
        denoms[(size_t)bh * SQ + q0 + t] = d;
        dinv[t] = 1.0f / d;
    }
    __syncthreads();

    const int b = bh >> 4, h = bh & 15;
#pragma unroll
    for (int ni = 0; ni < 4; ++ni)
#pragma unroll
        for (int r = 0; r < 4; ++r) {
            const int q = w * 16 + quad * 4 + r;
            const float v = acc[ni][r] * dinv[q];
            Ab[(size_t)(b * SQ + q0 + q) * Dm + h * 64 + ni * 16 + lm] = f2bf(v);
        }
}

// uncertainty = S / denom (fp32, output-1 region)
__global__ void write_unc(const float* __restrict__ denoms, float* __restrict__ unc)
{
    const int g = blockIdx.x * 256 + threadIdx.x;   // 0..65535
    unc[g] = (float)SQ / denoms[g];
}

extern "C" void kernel_launch(void* const* d_in, const int* in_sizes, int n_in,
                              void* d_out, int out_size, void* d_ws, size_t ws_size,
                              hipStream_t stream)
{
    const float* x   = (const float*)d_in[0];
    const float* qw  = (const float*)d_in[1];
    const float* qb  = (const float*)d_in[2];
    const float* kw  = (const float*)d_in[3];
    const float* kb  = (const float*)d_in[4];
    const float* vw  = (const float*)d_in[5];
    const float* vb  = (const float*)d_in[6];
    const float* ow  = (const float*)d_in[7];
    const float* ob  = (const float*)d_in[8];
    const float* esc = (const float*)d_in[9];
    const float* ebi = (const float*)d_in[10];

    float* out = (float*)d_out;                       // output 0: [B,S,D] fp32
    float* unc = out + (size_t)MM * Dm;               // output 1: [B,H,S] fp32

    // ws: [denoms 256KB | xb 8MB (reused as Ab) | Qb 8MB | Kb 8MB | Vb 8MB] = 32.25 MB
    float*          denoms = (float*)d_ws;
    unsigned short* xb = (unsigned short*)((char*)d_ws + (256 << 10));
    unsigned short* Qb = xb + (size_t)MM * Dm;
    unsigned short* Kb = Qb + (size_t)MM * Dm;
    unsigned short* Vb = Kb + (size_t)MM * Dm;
    unsigned short* Ab = xb;   // xb dead after QKV GEMMs; stream-ordered reuse

    cast_bf16<<<dim3(MM * Dm / 4 / 256), dim3(256), 0, stream>>>(
        (const float4*)x, (uint2*)xb, MM * Dm / 4);

    dim3 gG(Dm / 128, MM / 64);   // (8, 64)
    gemm_mfma<0><<<gG, dim3(256), 0, stream>>>(xb, qw, qb, Qb);
    gemm_mfma<0><<<gG, dim3(256), 0, stream>>>(xb, kw, kb, Kb);
    gemm_mfma<1><<<gG, dim3(256), 0, stream>>>(xb, vw, vb, Vb);

    attn_mfma<<<dim3(BB * NH * (SQ / 64)), dim3(256), 0, stream>>>(
        Qb, Kb, Vb, esc, ebi, Ab, denoms);

    write_unc<<<dim3(BB * NH * SQ / 256), dim3(256), 0, stream>>>(denoms, unc);

    gemm_mfma<2><<<gG, dim3(256), 0, stream>>>(Ab, ow, ob, out);
}

// Round 8
// 249.827 us; speedup vs baseline: 5.4450x; 1.2147x over previous
//
#include <hip/hip_runtime.h>

typedef __attribute__((ext_vector_type(8))) short bf16x8;  // 8 bf16 = 4 VGPRs (MFMA A/B frag)
typedef __attribute__((ext_vector_type(4))) float f32x4;   // MFMA C/D frag

constexpr int Dm  = 1024;    // d_model
constexpr int NH  = 16;      // heads
constexpr int HD  = 64;      // head dim
constexpr int SQ  = 2048;    // seq len
constexpr int BB  = 2;       // batch
constexpr int MM  = BB * SQ; // 4096 rows

// fp32 -> bf16 bits, round-to-nearest-even (finite values only)
__device__ __forceinline__ unsigned short f2bf(float f) {
    unsigned int u = __float_as_uint(f);
    u += 0x7FFFu + ((u >> 16) & 1u);
    return (unsigned short)(u >> 16);
}

// async global(16B) -> LDS, wave-uniform base + lane*16 pattern [m97]
__device__ __forceinline__ void gld16(const void* g, void* l) {
    __builtin_amdgcn_global_load_lds(
        (const __attribute__((address_space(1))) void*)g,
        (__attribute__((address_space(3))) void*)l, 16, 0, 0);
}

// ---------------------------------------------------------------------------
// One-shot cast of x + 4 weight matrices to bf16. 2,097,152 float4 segments:
// x: [0, 1048576) | qw/kw/vw/ow: 262144 each after it.
// ---------------------------------------------------------------------------
__global__ void cast_all(const float4* __restrict__ x,  const float4* __restrict__ qw,
                         const float4* __restrict__ kw, const float4* __restrict__ vw,
                         const float4* __restrict__ ow,
                         uint2* __restrict__ xb,  uint2* __restrict__ qwb,
                         uint2* __restrict__ kwb, uint2* __restrict__ vwb,
                         uint2* __restrict__ owb)
{
    int i = blockIdx.x * 256 + threadIdx.x;
    const float4* src; uint2* dst; int off;
    if      (i < 1048576) { src = x;  dst = xb;  off = i; }
    else if (i < 1310720) { src = qw; dst = qwb; off = i - 1048576; }
    else if (i < 1572864) { src = kw; dst = kwb; off = i - 1310720; }
    else if (i < 1835008) { src = vw; dst = vwb; off = i - 1572864; }
    else                  { src = ow; dst = owb; off = i - 1835008; }
    float4 v = src[off];
    uint2 o;
    o.x = (unsigned)f2bf(v.x) | ((unsigned)f2bf(v.y) << 16);
    o.y = (unsigned)f2bf(v.z) | ((unsigned)f2bf(v.w) << 16);
    dst[off] = o;
}

// ---------------------------------------------------------------------------
// m97-style MFMA GEMM core: C = A(bf16)[M,1024] @ W(bf16,[N,1024])^T + bias.
// 128x128 tile, BK=32, 256 thr = 4 waves (2x2), wave tile 64x64 (4x4 frags).
// Staging via global_load_lds dwordx4, contiguous LDS [row][32] (no pad).
// ---------------------------------------------------------------------------
template<typename EPI>
__device__ __forceinline__ void gemm_core(const unsigned short* __restrict__ A,
                                          const unsigned short* __restrict__ W,
                                          const float* __restrict__ bias,
                                          int n0, int m0, EPI epi)
{
    __shared__ unsigned short As[128 * 32];
    __shared__ unsigned short Ws[128 * 32];
    const int t    = threadIdx.x;
    const int lane = t & 63, w = t >> 6;
    const int lm   = lane & 15, quad = lane >> 4;
    const int wm   = w & 1, wn = w >> 1;

    const f32x4 fz = {0.f, 0.f, 0.f, 0.f};
    f32x4 acc[4][4];
#pragma unroll
    for (int mi = 0; mi < 4; ++mi)
#pragma unroll
        for (int ni = 0; ni < 4; ++ni) acc[mi][ni] = fz;

    float bsv[4];
#pragma unroll
    for (int ni = 0; ni < 4; ++ni) bsv[ni] = bias[n0 + wn * 64 + ni * 16 + lm];

    const int r0 = t >> 2,         ks0 = t & 3;          // seg j=0
    const int r1 = (t + 256) >> 2, ks1 = (t + 256) & 3;  // seg j=1

    for (int k0 = 0; k0 < 1024; k0 += 32) {
        __syncthreads();   // prev iter's ds_read done
        gld16(A + (size_t)(m0 + r0) * 1024 + k0 + ks0 * 8, &As[t * 8]);
        gld16(A + (size_t)(m0 + r1) * 1024 + k0 + ks1 * 8, &As[(t + 256) * 8]);
        gld16(W + (size_t)(n0 + r0) * 1024 + k0 + ks0 * 8, &Ws[t * 8]);
        gld16(W + (size_t)(n0 + r1) * 1024 + k0 + ks1 * 8, &Ws[(t + 256) * 8]);
        __syncthreads();   // compiler drains vmcnt before barrier

        bf16x8 af[4], bfr[4];
#pragma unroll
        for (int mi = 0; mi < 4; ++mi)
            af[mi] = *(const bf16x8*)&As[(wm * 64 + mi * 16 + lm) * 32 + quad * 8];
#pragma unroll
        for (int ni = 0; ni < 4; ++ni)
            bfr[ni] = *(const bf16x8*)&Ws[(wn * 64 + ni * 16 + lm) * 32 + quad * 8];
#pragma unroll
        for (int mi = 0; mi < 4; ++mi)
#pragma unroll
            for (int ni = 0; ni < 4; ++ni)
                acc[mi][ni] = __builtin_amdgcn_mfma_f32_16x16x32_bf16(
                                  af[mi], bfr[ni], acc[mi][ni], 0, 0, 0);
    }

    // C/D layout: col = lane&15, row = quad*4 + reg  [verified m89/m91]
#pragma unroll
    for (int mi = 0; mi < 4; ++mi)
#pragma unroll
        for (int ni = 0; ni < 4; ++ni)
#pragma unroll
            for (int r = 0; r < 4; ++r) {
                const int m = m0 + wm * 64 + mi * 16 + quad * 4 + r;
                const int n = n0 + wn * 64 + ni * 16 + lm;
                epi(m, n, acc[mi][ni][r] + bsv[ni]);
            }
}

// fused QKV projection; z selects weight/bias/dst. Q,K head-split; V transposed.
__global__ __launch_bounds__(256) void gemm_qkv(
    const unsigned short* __restrict__ xb,
    const unsigned short* __restrict__ qwb, const float* __restrict__ qb,
    const unsigned short* __restrict__ kwb, const float* __restrict__ kb,
    const unsigned short* __restrict__ vwb, const float* __restrict__ vb,
    unsigned short* __restrict__ Qb, unsigned short* __restrict__ Kb,
    unsigned short* __restrict__ Vb)
{
    const int z = blockIdx.z;
    const unsigned short* W = (z == 0) ? qwb : (z == 1) ? kwb : vwb;
    const float* bias       = (z == 0) ? qb  : (z == 1) ? kb  : vb;
    unsigned short* dst     = (z == 0) ? Qb  : (z == 1) ? Kb  : Vb;
    const int n0 = blockIdx.x * 128, m0 = blockIdx.y * 128;
    const bool vt = (z == 2);

    gemm_core(xb, W, bias, n0, m0, [&](int m, int n, float v) {
        const int b = m >> 11, s = m & 2047, h = n >> 6, hd = n & 63;
        const size_t idx = vt ? ((size_t)((b * NH + h) * 64 + hd) * SQ + s)
                              : ((size_t)((b * NH + h) * SQ + s) * 64 + hd);
        dst[idx] = f2bf(v);
    });
}

// final projection: fp32 row-major out
__global__ __launch_bounds__(256) void gemm_out(
    const unsigned short* __restrict__ Ab, const unsigned short* __restrict__ owb,
    const float* __restrict__ ob, float* __restrict__ out)
{
    const int n0 = blockIdx.x * 128, m0 = blockIdx.y * 128;
    gemm_core(Ab, owb, ob, n0, m0, [&](int m, int n, float v) {
        out[(size_t)m * 1024 + n] = v;
    });
}

// ---------------------------------------------------------------------------
// MFMA evidential attention. Block = (b,h) x 64-query tile; 4 waves x 16q.
// LDS stride 88 ushort (176B): 16B-aligned, ~2-way banks on frag reads.
// Writes Ab (bf16 [B,S,D]) + unc (fp32, output-1) directly.
// ---------------------------------------------------------------------------
constexpr int ST = 88;

__global__ __launch_bounds__(256) void attn_mfma(const unsigned short* __restrict__ Qg,
                                                 const unsigned short* __restrict__ Kg,
                                                 const unsigned short* __restrict__ Vtg,
                                                 const float* __restrict__ esc,
                                                 const float* __restrict__ ebi,
                                                 unsigned short* __restrict__ Ab,
                                                 float* __restrict__ unc)
{
    __shared__ unsigned short Qs[64 * ST];
    __shared__ unsigned short Ks[64 * ST];
    __shared__ unsigned short Vts[64 * ST];     // [d][k_seq]
    __shared__ unsigned short Es[4 * 16 * ST];  // wave-private E strips [q][k_seq]
    __shared__ float dred[64][17];
    __shared__ float dinv[64];

    const int t    = threadIdx.x;
    const int lane = t & 63, w = t >> 6;
    const int lm   = lane & 15, quad = lane >> 4;
    const int qt   = blockIdx.x & 31;    // 32 query tiles
    const int bh   = blockIdx.x >> 5;    // b*NH + h
    const int q0   = qt * 64;

    const float scale = esc[0];
    const float bias1 = 1.0f + ebi[0];

    // stage Q tile (rows=q, cols=d)
    {
        const unsigned short* g = Qg + (size_t)(bh * SQ + q0) * 64;
#pragma unroll
        for (int i = 0; i < 2; ++i) {
            int seg = t + 256 * i, r = seg >> 3, c8 = seg & 7;
            *(uint4*)&Qs[r * ST + c8 * 8] = *(const uint4*)(g + r * 64 + c8 * 8);
        }
    }

    const f32x4 fz = {0.f, 0.f, 0.f, 0.f};
    f32x4 acc[4];
#pragma unroll
    for (int ni = 0; ni < 4; ++ni) acc[ni] = fz;
    float drow[4] = {0.f, 0.f, 0.f, 0.f};

    for (int kt = 0; kt < 32; ++kt) {
        __syncthreads();   // prev iter's Ks/Vts readers done (Qs visible 1st iter)
        {
            const unsigned short* kg = Kg  + (size_t)(bh * SQ + kt * 64) * 64;
            const unsigned short* vg = Vtg + (size_t)bh * 64 * SQ + kt * 64;
#pragma unroll
            for (int i = 0; i < 2; ++i) {
                int seg = t + 256 * i, r = seg >> 3, c8 = seg & 7;
                *(uint4*)&Ks[r * ST + c8 * 8]  = *(const uint4*)(kg + r * 64 + c8 * 8);
                *(uint4*)&Vts[r * ST + c8 * 8] = *(const uint4*)(vg + (size_t)r * SQ + c8 * 8);
            }
        }
        __syncthreads();

        // S = Q K^T : A-frag = Q strip rows, B-frag = K rows
        bf16x8 qa[2];
#pragma unroll
        for (int kc = 0; kc < 2; ++kc)
            qa[kc] = *(const bf16x8*)&Qs[(w * 16 + lm) * ST + kc * 32 + quad * 8];
#pragma unroll
        for (int ni = 0; ni < 4; ++ni) {
            f32x4 s = fz;
#pragma unroll
            for (int kc = 0; kc < 2; ++kc) {
                bf16x8 kb = *(const bf16x8*)&Ks[(ni * 16 + lm) * ST + kc * 32 + quad * 8];
                s = __builtin_amdgcn_mfma_f32_16x16x32_bf16(qa[kc], kb, s, 0, 0, 0);
            }
#pragma unroll
            for (int r = 0; r < 4; ++r) {
                float ev = __expf(s[r] * 0.125f) * scale + bias1;
                drow[r] += ev;
                Es[w * 16 * ST + (quad * 4 + r) * ST + ni * 16 + lm] = f2bf(ev);
            }
        }
        __syncthreads();   // Es cross-lane visibility

        // acc += E V : A-frag = E strip rows, B-frag = Vt rows (d), k = k_seq
        bf16x8 ea[2];
#pragma unroll
        for (int kc = 0; kc < 2; ++kc)
            ea[kc] = *(const bf16x8*)&Es[w * 16 * ST + lm * ST + kc * 32 + quad * 8];
#pragma unroll
        for (int ni = 0; ni < 4; ++ni)
#pragma unroll
            for (int kc = 0; kc < 2; ++kc) {
                bf16x8 vb = *(const bf16x8*)&Vts[(ni * 16 + lm) * ST + kc * 32 + quad * 8];
                acc[ni] = __builtin_amdgcn_mfma_f32_16x16x32_bf16(ea[kc], vb, acc[ni], 0, 0, 0);
            }
    }

    // denom reduce + uncertainty
    __syncthreads();
#pragma unroll
    for (int r = 0; r < 4; ++r)
        dred[w * 16 + quad * 4 + r][lm] = drow[r];
    __syncthreads();
    if (t < 64) {
        float d = 0.f;
#pragma unroll
        for (int c = 0; c < 16; ++c) d += dred[t][c];
        unc[(size_t)bh * SQ + q0 + t] = (float)SQ / d;
        dinv[t] = 1.0f / d;
    }
    __syncthreads();

    const int b = bh >> 4, h = bh & 15;
#pragma unroll
    for (int ni = 0; ni < 4; ++ni)
#pragma unroll
        for (int r = 0; r < 4; ++r) {
            const int q = w * 16 + quad * 4 + r;
            const float v = acc[ni][r] * dinv[q];
            Ab[(size_t)(b * SQ + q0 + q) * Dm + h * 64 + ni * 16 + lm] = f2bf(v);
        }
}

extern "C" void kernel_launch(void* const* d_in, const int* in_sizes, int n_in,
                              void* d_out, int out_size, void* d_ws, size_t ws_size,
                              hipStream_t stream)
{
    const float* x   = (const float*)d_in[0];
    const float* qw  = (const float*)d_in[1];
    const float* qb  = (const float*)d_in[2];
    const float* kw  = (const float*)d_in[3];
    const float* kb  = (const float*)d_in[4];
    const float* vw  = (const float*)d_in[5];
    const float* vb  = (const float*)d_in[6];
    const float* ow  = (const float*)d_in[7];
    const float* ob  = (const float*)d_in[8];
    const float* esc = (const float*)d_in[9];
    const float* ebi = (const float*)d_in[10];

    float* out = (float*)d_out;                 // output 0: [B,S,D] fp32 (16 MB)
    float* unc = out + (size_t)MM * Dm;         // output 1: [B,H,S] fp32

    // ws (24 MB): xb 8MB @0 (reused as Ab) | qwb/kwb/vwb/owb 2MB @8/10/12/14MB | Vb 8MB @16MB
    unsigned short* xb  = (unsigned short*)d_ws;
    unsigned short* qwb = (unsigned short*)((char*)d_ws + (8u  << 20));
    unsigned short* kwb = (unsigned short*)((char*)d_ws + (10u << 20));
    unsigned short* vwb = (unsigned short*)((char*)d_ws + (12u << 20));
    unsigned short* owb = (unsigned short*)((char*)d_ws + (14u << 20));
    unsigned short* Vb  = (unsigned short*)((char*)d_ws + (16u << 20));
    unsigned short* Ab  = xb;                   // xb dead after QKV GEMMs

    // Q,K tiles live in d_out's output-0 region (16 MB), dead before gemm_out
    unsigned short* Qb = (unsigned short*)d_out;
    unsigned short* Kb = Qb + (size_t)MM * Dm;  // second 8 MB

    cast_all<<<dim3(2097152 / 256), dim3(256), 0, stream>>>(
        (const float4*)x, (const float4*)qw, (const float4*)kw,
        (const float4*)vw, (const float4*)ow,
        (uint2*)xb, (uint2*)qwb, (uint2*)kwb, (uint2*)vwb, (uint2*)owb);

    gemm_qkv<<<dim3(Dm / 128, MM / 128, 3), dim3(256), 0, stream>>>(
        xb, qwb, qb, kwb, kb, vwb, vb, Qb, Kb, Vb);

    attn_mfma<<<dim3(BB * NH * (SQ / 64)), dim3(256), 0, stream>>>(
        Qb, Kb, Vb, esc, ebi, Ab, unc);

    gemm_out<<<dim3(Dm / 128, MM / 128), dim3(256), 0, stream>>>(Ab, owb, ob, out);
}